// Round 7
// baseline (7273.726 us; speedup 1.0000x reference)
//
#include <hip/hip_runtime.h>
#include <stdint.h>

// FPS: B=16, C=3, N=131072, M=2048. 256 blocks (16/batch) x 1024 thr, 1/CU.
//
// R7 = R6 minus ALL intra-block barriers (no __syncthreads in the loop):
//  - Per-iteration LDS words (Lkey/Lmask/Wwin[t], never reused -> no reset
//    races): waves combine via ds_max + ds_or; the mask-completing wave
//    publishes the block key immediately (no barrier join, no wave0 wait).
//  - wave0 remains the ONLY fabric poller (R4/R6-proven; R3 showed
//    all-wave polling explodes fabric traffic). It broadcasts the tagged
//    winner through LDS word Wwin[t]; waves 1..15 spin locally (~30 cyc).
//  - Centroid via readfirstlane -> scalar loads (points never written
//    during kernel, so scalar cache is safe).
//  - Coords pinned in regs/AGPRs via asm (R6; VGPR=28 + AGPR spill is fine).
// Safety: block publishes t+1 only after all its waves detected t => no
// wave can still be polling t when parity slot (t&1) is rewritten at t+2.
// Numerics (bit-matches XLA-CPU ref, verified R2..R6):
//   d = fma(dz,dz, fma(dy,dy, dx*dx)); key=[distBits:32][invIdx:17], tag@49.

#define NBATCH    16
#define NPTS      131072
#define SUBBLOCKS 16
#define NTHREADS  1024
#define NWAVES    16
#define CHUNK     8192
#define HALF      4096
#define MMAX      2048

typedef unsigned long long u64;

__device__ __forceinline__ u64 umax64(u64 a, u64 b) { return a > b ? a : b; }

__global__ __launch_bounds__(NTHREADS, 4)
void fps_kernel(const float* __restrict__ points,
                float* __restrict__ out,
                u64* __restrict__ slots, int M)
{
  __shared__ u64      Lkey[MMAX];   // block-combine max key, word per iter
  __shared__ unsigned Lmask[MMAX];  // wave-arrival bitmask, word per iter
  __shared__ u64      Wwin[MMAX];   // tagged batch winner, word per iter

  const int bid   = blockIdx.x;
  const int xcd   = bid & 7;                 // XCD swizzle (speed only)
  const int ord   = bid >> 3;
  const int batch = xcd * 2 + (ord >> 4);
  const int sub   = ord & 15;
  const int tid   = threadIdx.x;
  const int wave  = tid >> 6;
  const int lane  = tid & 63;

  const float* __restrict__ px = points + (size_t)batch * 3 * NPTS;
  const float* __restrict__ py = px + NPTS;
  const float* __restrict__ pz = px + 2 * NPTS;
  float* outb = out + (size_t)batch * 3 * M;
  u64* bslots = slots + (size_t)batch * 2 * SUBBLOCKS;

  // One-time zero of the per-iteration LDS words.
  for (int i = tid; i < MMAX; i += NTHREADS) {
    Lkey[i] = 0; Lmask[i] = 0; Wwin[i] = 0;
  }

  const int cbase = sub * CHUNK;
  const int g0 = cbase + (tid << 2);
  const int g1 = g0 + HALF;

  float4 A0 = *(const float4*)(px + g0);
  float4 B0 = *(const float4*)(py + g0);
  float4 C0 = *(const float4*)(pz + g0);
  float4 A1 = *(const float4*)(px + g1);
  float4 B1 = *(const float4*)(py + g1);
  float4 C1 = *(const float4*)(pz + g1);
  float x0=A0.x, x1=A0.y, x2=A0.z, x3=A0.w, x4=A1.x, x5=A1.y, x6=A1.z, x7=A1.w;
  float y0=B0.x, y1=B0.y, y2=B0.z, y3=B0.w, y4=B1.x, y5=B1.y, y6=B1.z, y7=B1.w;
  float z0=C0.x, z1=C0.y, z2=C0.z, z3=C0.w, z4=C1.x, z5=C1.y, z6=C1.z, z7=C1.w;
  // Pin coords (opaque to optimizer; lands in VGPR/AGPR unified file).
  asm volatile("" :
    "+v"(x0),"+v"(x1),"+v"(x2),"+v"(x3),"+v"(x4),"+v"(x5),"+v"(x6),"+v"(x7),
    "+v"(y0),"+v"(y1),"+v"(y2),"+v"(y3),"+v"(y4),"+v"(y5),"+v"(y6),"+v"(y7),
    "+v"(z0),"+v"(z1),"+v"(z2),"+v"(z3),"+v"(z4),"+v"(z5),"+v"(z6),"+v"(z7));

  float d0, d1, d2, d3, d4, d5, d6, d7;
  d0 = d1 = d2 = d3 = d4 = d5 = d6 = d7 = __builtin_inff();

  float cx = px[0], cy = py[0], cz = pz[0];
  if (sub == 0 && tid == 0) { outb[0] = cx; outb[M] = cy; outb[2 * M] = cz; }

  __syncthreads();   // one-time: LDS zero-init complete

  for (int t = 1; t < M; ++t) {
    float best = -1.0f;
    int bidx = 0;
    // d = fma(dz,dz, fma(dy,dy, dx*dx)); ascending index => first-max kept.
#define STEP(XX, YY, ZZ, DREG, IDX) { \
    float dx = __fsub_rn((XX), cx); \
    float dy = __fsub_rn((YY), cy); \
    float dz = __fsub_rn((ZZ), cz); \
    float dd = __builtin_fmaf(dz, dz, __builtin_fmaf(dy, dy, __fmul_rn(dx, dx))); \
    DREG = DREG < dd ? DREG : dd; \
    if (DREG > best) { best = DREG; bidx = (IDX); } }
    STEP(x0, y0, z0, d0, g0 + 0)
    STEP(x1, y1, z1, d1, g0 + 1)
    STEP(x2, y2, z2, d2, g0 + 2)
    STEP(x3, y3, z3, d3, g0 + 3)
    STEP(x4, y4, z4, d4, g1 + 0)
    STEP(x5, y5, z5, d5, g1 + 1)
    STEP(x6, y6, z6, d6, g1 + 2)
    STEP(x7, y7, z7, d7, g1 + 3)

    u64 key = ((u64)__float_as_uint(best) << 17) | (u64)((NPTS - 1) - bidx);

    // Per-wave butterfly (parallel across all 16 waves).
#pragma unroll
    for (int m = 32; m >= 1; m >>= 1) {
      u64 o = __shfl_xor(key, m, 64);
      key = umax64(key, o);
    }

    u64* par = bslots + (size_t)(t & 1) * SUBBLOCKS;

    // Barrier-free block combine: ds_max then ds_or (DS pipe is per-wave
    // in-order); the wave completing the mask re-reads the final max
    // (control-dependent on the or result) and publishes immediately.
    if (lane == 0) {
      atomicMax((u64*)&Lkey[t], key);
      unsigned old = atomicOr(&Lmask[t], 1u << wave);
      if ((old | (1u << wave)) == 0xFFFFu) {
        u64 fk = __hip_atomic_load(&Lkey[t], __ATOMIC_RELAXED,
                                   __HIP_MEMORY_SCOPE_WORKGROUP);
        __hip_atomic_store(par + sub, ((u64)t << 49) | fk,
                           __ATOMIC_RELAXED, __HIP_MEMORY_SCOPE_AGENT);
      }
    }

    u64 wk;
    if (wave == 0) {
      // Sole fabric poller: converged (one 128 B line/round), 2-deep pipelined.
      const u64* pp = par + (lane & 15);
      u64 va = __hip_atomic_load(pp, __ATOMIC_RELAXED, __HIP_MEMORY_SCOPE_AGENT);
      u64 vb = __hip_atomic_load(pp, __ATOMIC_RELAXED, __HIP_MEMORY_SCOPE_AGENT);
      u64 v;
      for (;;) {
        if (__ballot((unsigned)(va >> 49) == (unsigned)t) == ~0ull) { v = va; break; }
        va = vb;
        vb = __hip_atomic_load(pp, __ATOMIC_RELAXED, __HIP_MEMORY_SCOPE_AGENT);
      }
#pragma unroll
      for (int m = 8; m >= 1; m >>= 1) {
        u64 o = __shfl_xor(v, m, 64);
        v = umax64(v, o);
      }
      if (lane == 0) {
        __hip_atomic_store(&Wwin[t], v, __ATOMIC_RELAXED,
                           __HIP_MEMORY_SCOPE_WORKGROUP);
      }
      wk = v;
    } else {
      // Local LDS spin (~30 cyc granularity), no fabric traffic.
      do {
        wk = __hip_atomic_load(&Wwin[t], __ATOMIC_RELAXED,
                               __HIP_MEMORY_SCOPE_WORKGROUP);
      } while ((unsigned)(wk >> 49) != (unsigned)t);
    }

    // Centroid: scalar-promoted broadcast loads (points is read-only).
    int ssel = __builtin_amdgcn_readfirstlane(
                 (int)(NPTS - 1) - (int)(wk & 0x1FFFF));
    cx = px[ssel]; cy = py[ssel]; cz = pz[ssel];

    if (sub == 0 && tid == 0) {
      outb[t]         = cx;
      outb[M + t]     = cy;
      outb[2 * M + t] = cz;
    }
  }
}

extern "C" void kernel_launch(void* const* d_in, const int* in_sizes, int n_in,
                              void* d_out, int out_size, void* d_ws, size_t ws_size,
                              hipStream_t stream) {
  (void)in_sizes; (void)n_in; (void)ws_size;
  const float* points = (const float*)d_in[0];
  float* out = (float*)d_out;
  u64* slots = (u64*)d_ws;
  const int M = out_size / (NBATCH * 3);   // 2048 (MMAX bound)

  // Zero barrier slots (stale tags must not alias t in 1..M-1).
  hipMemsetAsync(d_ws, 0, (size_t)NBATCH * 2 * SUBBLOCKS * sizeof(u64), stream);

  hipLaunchKernelGGL(fps_kernel, dim3(NBATCH * SUBBLOCKS), dim3(NTHREADS), 0,
                     stream, points, out, slots, M);
}

// Round 8
// 4800.266 us; speedup vs baseline: 1.5153x; 1.5153x over previous
//
#include <hip/hip_runtime.h>
#include <stdint.h>

// FPS: B=16, C=3, N=131072, M=2048. 256 blocks (16/batch) x 1024 thr, 1/CU.
//
// R8 = R6 (best: 4.13 ms) + XCD-local L2 fast-path barrier with device-scope
// fallback. R6 budget: ~1.1 us of the 2.0 us period is agent-scope
// store->poll-detect RTT (memory-side coherence point). If a batch's 16
// blocks land on one XCD (bid&7 heuristic), plain sc0 stores/loads talk
// through that XCD's L2 (~0.15 us RTT). Mapping is UNDEFINED -> publishers
// write BOTH paths; the poller tight-polls L2 and checks the device line
// every 4th round. Wrong mapping just means the L2 ballot never passes.
//  - L2 slot = 2 self-tagged dwords (tear-proof; tag = t&255; parity-2 reuse
//    => stale tag is t-2 mod 256, never equal to t).
//  - R7 lesson kept: no spinning waves (syncthreads sleepers), single
//    converged poller, 1-line poll region, vector centroid loads.
// Numerics (bit-matches XLA-CPU ref, verified R2..R7):
//   d = fma(dz,dz, fma(dy,dy, dx*dx)); key=[distBits:32][invIdx:17], tag@49.

#define NBATCH    16
#define NPTS      131072
#define SUBBLOCKS 16
#define NTHREADS  1024
#define CHUNK     8192
#define HALF      4096

typedef unsigned long long u64;
typedef unsigned int u32;

__device__ __forceinline__ u64 umax64(u64 a, u64 b) { return a > b ? a : b; }

__global__ __launch_bounds__(NTHREADS, 4)
void fps_kernel(const float* __restrict__ points,
                float* __restrict__ out,
                u64* __restrict__ dslots,      // device-scope slots (R6 path)
                u32* __restrict__ lslots,      // XCD-L2 fast-path slots
                int M)
{
  __shared__ u64 wkeys[NTHREADS / 64];
  __shared__ u64 winner_s;

  const int bid   = blockIdx.x;
  const int xcd   = bid & 7;                 // co-location heuristic
  const int ord   = bid >> 3;
  const int batch = xcd * 2 + (ord >> 4);
  const int sub   = ord & 15;
  const int tid   = threadIdx.x;
  const int wave  = tid >> 6;
  const int lane  = tid & 63;

  const float* __restrict__ px = points + (size_t)batch * 3 * NPTS;
  const float* __restrict__ py = px + NPTS;
  const float* __restrict__ pz = px + 2 * NPTS;
  float* outb = out + (size_t)batch * 3 * M;
  u64* dbase = dslots + (size_t)batch * 2 * SUBBLOCKS;
  u32* lbase = lslots + (size_t)batch * 64;          // 2 parity * 16 slots * 2 dw

  const int cbase = sub * CHUNK;
  const int g0 = cbase + (tid << 2);
  const int g1 = g0 + HALF;

  float4 A0 = *(const float4*)(px + g0);
  float4 B0 = *(const float4*)(py + g0);
  float4 C0 = *(const float4*)(pz + g0);
  float4 A1 = *(const float4*)(px + g1);
  float4 B1 = *(const float4*)(py + g1);
  float4 C1 = *(const float4*)(pz + g1);
  float x0=A0.x, x1=A0.y, x2=A0.z, x3=A0.w, x4=A1.x, x5=A1.y, x6=A1.z, x7=A1.w;
  float y0=B0.x, y1=B0.y, y2=B0.z, y3=B0.w, y4=B1.x, y5=B1.y, y6=B1.z, y7=B1.w;
  float z0=C0.x, z1=C0.y, z2=C0.z, z3=C0.w, z4=C1.x, z5=C1.y, z6=C1.z, z7=C1.w;
  // Pin coords (opaque to optimizer; prevents in-loop rematerialization).
  asm volatile("" :
    "+v"(x0),"+v"(x1),"+v"(x2),"+v"(x3),"+v"(x4),"+v"(x5),"+v"(x6),"+v"(x7),
    "+v"(y0),"+v"(y1),"+v"(y2),"+v"(y3),"+v"(y4),"+v"(y5),"+v"(y6),"+v"(y7),
    "+v"(z0),"+v"(z1),"+v"(z2),"+v"(z3),"+v"(z4),"+v"(z5),"+v"(z6),"+v"(z7));

  float d0r, d1r, d2r, d3r, d4r, d5r, d6r, d7r;
  d0r = d1r = d2r = d3r = d4r = d5r = d6r = d7r = __builtin_inff();

  float cx = px[0], cy = py[0], cz = pz[0];
  if (sub == 0 && tid == 0) { outb[0] = cx; outb[M] = cy; outb[2 * M] = cz; }

  int sel = 0;
  for (int t = 1; t < M; ++t) {
    float best = -1.0f;
    int bidx = 0;
    // d = fma(dz,dz, fma(dy,dy, dx*dx)); ascending index => first-max kept.
#define STEP(XX, YY, ZZ, DREG, IDX) { \
    float dx = __fsub_rn((XX), cx); \
    float dy = __fsub_rn((YY), cy); \
    float dz = __fsub_rn((ZZ), cz); \
    float dd = __builtin_fmaf(dz, dz, __builtin_fmaf(dy, dy, __fmul_rn(dx, dx))); \
    DREG = DREG < dd ? DREG : dd; \
    if (DREG > best) { best = DREG; bidx = (IDX); } }
    STEP(x0, y0, z0, d0r, g0 + 0)
    STEP(x1, y1, z1, d1r, g0 + 1)
    STEP(x2, y2, z2, d2r, g0 + 2)
    STEP(x3, y3, z3, d3r, g0 + 3)
    STEP(x4, y4, z4, d4r, g1 + 0)
    STEP(x5, y5, z5, d5r, g1 + 1)
    STEP(x6, y6, z6, d6r, g1 + 2)
    STEP(x7, y7, z7, d7r, g1 + 3)

    u64 key = ((u64)__float_as_uint(best) << 17) | (u64)((NPTS - 1) - bidx);

    // Per-wave butterfly (parallel across all 16 waves).
#pragma unroll
    for (int m = 32; m >= 1; m >>= 1) {
      u64 o = __shfl_xor(key, m, 64);
      key = umax64(key, o);
    }
    if (lane == 0) wkeys[wave] = key;
    __syncthreads();

    if (wave == 0) {
      u64 k = wkeys[lane & 15];
#pragma unroll
      for (int m = 8; m >= 1; m >>= 1) {
        u64 o = __shfl_xor(k, m, 64);
        k = umax64(k, o);
      }
      const u32 tag8 = (u32)t & 255u;
      u64* dpar = dbase + (size_t)(t & 1) * SUBBLOCKS;
      u32* lpar = lbase + (size_t)(t & 1) * 32;

      if (lane == 0) {
        // L2 fast-path publish: two self-tagged dwords (tear-proof).
        u32 D = (u32)(k >> 17);
        int  g = (int)(NPTS - 1) - (int)(k & 0x1FFFF);   // in OUR chunk
        u32  L = (u32)(8191 - (g - cbase));              // 13-bit local inv
        u32 w0 = (tag8 << 24) | (D >> 8);
        u32 w1 = (tag8 << 24) | ((D & 0xFFu) << 16) | (L << 3);
        u64 both = ((u64)w1 << 32) | w0;
        const u32* lp = lpar + sub * 2;
        asm volatile("global_store_dwordx2 %0, %1, off sc0"
                     :: "v"(lp), "v"(both) : "memory");
        // Device-scope publish (always-correct fallback).
        __hip_atomic_store(dpar + sub, ((u64)t << 49) | k,
                           __ATOMIC_RELAXED, __HIP_MEMORY_SCOPE_AGENT);
      }

      // Single converged poller: tight L2 rounds, device check every 4th.
      const u32* lpp = lpar + (lane & 15) * 2;
      const u64* dpp = dpar + (lane & 15);
      u64 win;
      int round = 0;
      for (;;) {
        u64 raw;
        asm volatile("global_load_dwordx2 %0, %1, off sc0\n\t"
                     "s_waitcnt vmcnt(0)"
                     : "=v"(raw) : "v"(lpp) : "memory");
        u32 a0 = (u32)raw, a1 = (u32)(raw >> 32);
        bool ok = ((a0 >> 24) == tag8) & ((a1 >> 24) == tag8);
        if (__ballot(ok) == ~0ull) {
          u32 D = ((a0 & 0xFFFFFFu) << 8) | ((a1 >> 16) & 0xFFu);
          int  L = (int)((a1 >> 3) & 0x1FFFu);
          int  g = (lane & 15) * CHUNK + (8191 - L);
          u64 kk = ((u64)D << 17) | (u64)((NPTS - 1) - g);
#pragma unroll
          for (int m = 8; m >= 1; m >>= 1) {
            u64 o = __shfl_xor(kk, m, 64);
            kk = umax64(kk, o);
          }
          win = ((u64)t << 49) | kk;
          break;
        }
        if ((++round & 3) == 0) {
          u64 v = __hip_atomic_load(dpp, __ATOMIC_RELAXED,
                                    __HIP_MEMORY_SCOPE_AGENT);
          if (__ballot((unsigned)(v >> 49) == (unsigned)t) == ~0ull) {
#pragma unroll
            for (int m = 8; m >= 1; m >>= 1) {
              u64 o = __shfl_xor(v, m, 64);
              v = umax64(v, o);
            }
            win = v;   // same value as fast path (tag @49 identical)
            break;
          }
        }
      }
      if (lane == 0) winner_s = win;
    }
    __syncthreads();

    sel = (NPTS - 1) - (int)(winner_s & 0x1FFFF);
    cx = px[sel]; cy = py[sel]; cz = pz[sel];

    if (sub == 0 && tid == 0) {
      outb[t]         = cx;
      outb[M + t]     = cy;
      outb[2 * M + t] = cz;
    }
  }
}

extern "C" void kernel_launch(void* const* d_in, const int* in_sizes, int n_in,
                              void* d_out, int out_size, void* d_ws, size_t ws_size,
                              hipStream_t stream) {
  (void)in_sizes; (void)n_in; (void)ws_size;
  const float* points = (const float*)d_in[0];
  float* out = (float*)d_out;
  u64* dslots = (u64*)d_ws;                                  // 4 KB
  u32* lslots = (u32*)((char*)d_ws + 4096);                  // 4 KB
  const int M = out_size / (NBATCH * 3);   // 2048

  // Zero both slot regions (stale tags must not alias round tags).
  hipMemsetAsync(d_ws, 0, 8192, stream);

  hipLaunchKernelGGL(fps_kernel, dim3(NBATCH * SUBBLOCKS), dim3(NTHREADS), 0,
                     stream, points, out, dslots, lslots, M);
}

// Round 9
// 4125.829 us; speedup vs baseline: 1.7630x; 1.1635x over previous
//
#include <hip/hip_runtime.h>
#include <stdint.h>

// FPS: B=16, C=3, N=131072, M=2048. 256 blocks (16/batch) x 1024 thr, 1/CU.
//
// R9 = R6 (best verified protocol: 4.13 ms) with the barrier slots accessed
// via ATOMIC RMW instead of store/load.
// Evidence: R6 WRITE_SIZE = 16.76 MB = 2047 x 256 x 32 B exactly -> every
// 8 B agent-scope slot STORE writes a 32 B sector through to HBM; the
// barrier bounces off DRAM (~0.9 us RTT, m126). Device-scope atomic RMWs
// execute at the MALL atomic units on L3-RESIDENT lines (writeback only on
// eviction): publish = atomicExch, poll = fetch_add(0). Expect slot traffic
// to vanish from FETCH/WRITE and RTT to drop to L3-class.
//  - Poll: lanes 0..15 RMW 16 DISTINCT slots (same-address RMWs serialize;
//    lanes 16..63 sit out, ballot counts them satisfied).
//  - R8 lesson: bid&7 XCD co-location is FALSE on this part; no L2 fast path.
//  - R7 lesson: keep syncthreads (sleeping waves); no LDS spinners.
// Numerics (bit-matches XLA-CPU ref, verified R2..R8):
//   d = fma(dz,dz, fma(dy,dy, dx*dx)); key=[distBits:32][invIdx:17], tag@49.

#define NBATCH    16
#define NPTS      131072
#define SUBBLOCKS 16
#define NTHREADS  1024
#define CHUNK     8192
#define HALF      4096

typedef unsigned long long u64;

__device__ __forceinline__ u64 umax64(u64 a, u64 b) { return a > b ? a : b; }

__global__ __launch_bounds__(NTHREADS, 4)
void fps_kernel(const float* __restrict__ points,
                float* __restrict__ out,
                u64* __restrict__ slots, int M)
{
  __shared__ u64 wkeys[NTHREADS / 64];
  __shared__ u64 winner_s;

  const int bid   = blockIdx.x;
  const int xcd   = bid & 7;
  const int ord   = bid >> 3;
  const int batch = xcd * 2 + (ord >> 4);
  const int sub   = ord & 15;
  const int tid   = threadIdx.x;
  const int wave  = tid >> 6;
  const int lane  = tid & 63;

  const float* __restrict__ px = points + (size_t)batch * 3 * NPTS;
  const float* __restrict__ py = px + NPTS;
  const float* __restrict__ pz = px + 2 * NPTS;
  float* outb = out + (size_t)batch * 3 * M;
  u64* bslots = slots + (size_t)batch * 2 * SUBBLOCKS;

  const int cbase = sub * CHUNK;
  const int g0 = cbase + (tid << 2);
  const int g1 = g0 + HALF;

  // Load this thread's 8 points (2 x float4 per plane, coalesced).
  float4 A0 = *(const float4*)(px + g0);
  float4 B0 = *(const float4*)(py + g0);
  float4 C0 = *(const float4*)(pz + g0);
  float4 A1 = *(const float4*)(px + g1);
  float4 B1 = *(const float4*)(py + g1);
  float4 C1 = *(const float4*)(pz + g1);
  float x0=A0.x, x1=A0.y, x2=A0.z, x3=A0.w, x4=A1.x, x5=A1.y, x6=A1.z, x7=A1.w;
  float y0=B0.x, y1=B0.y, y2=B0.z, y3=B0.w, y4=B1.x, y5=B1.y, y6=B1.z, y7=B1.w;
  float z0=C0.x, z1=C0.y, z2=C0.z, z3=C0.w, z4=C1.x, z5=C1.y, z6=C1.z, z7=C1.w;
  // Pin coords (opaque to optimizer; prevents in-loop rematerialization —
  // R2/R3 showed the compiler otherwise re-reads them every iteration).
  asm volatile("" :
    "+v"(x0),"+v"(x1),"+v"(x2),"+v"(x3),"+v"(x4),"+v"(x5),"+v"(x6),"+v"(x7),
    "+v"(y0),"+v"(y1),"+v"(y2),"+v"(y3),"+v"(y4),"+v"(y5),"+v"(y6),"+v"(y7),
    "+v"(z0),"+v"(z1),"+v"(z2),"+v"(z3),"+v"(z4),"+v"(z5),"+v"(z6),"+v"(z7));

  float d0, d1, d2, d3, d4, d5, d6, d7;
  d0 = d1 = d2 = d3 = d4 = d5 = d6 = d7 = __builtin_inff();

  // Selection 0 is index 0 by convention.
  if (sub == 0 && tid == 0) {
    outb[0]     = px[0];
    outb[M]     = py[0];
    outb[2 * M] = pz[0];
  }

  int sel = 0;
  for (int t = 1; t < M; ++t) {
    // Centroid = previously selected point (uniform broadcast loads, L2-hot).
    float cx = px[sel], cy = py[sel], cz = pz[sel];

    float best = -1.0f;
    int bidx = 0;
    // d = fma(dz,dz, fma(dy,dy, dx*dx)); ascending index => first-max kept.
#define STEP(XX, YY, ZZ, DREG, IDX) { \
    float dx = __fsub_rn((XX), cx); \
    float dy = __fsub_rn((YY), cy); \
    float dz = __fsub_rn((ZZ), cz); \
    float dd = __builtin_fmaf(dz, dz, __builtin_fmaf(dy, dy, __fmul_rn(dx, dx))); \
    DREG = DREG < dd ? DREG : dd; \
    if (DREG > best) { best = DREG; bidx = (IDX); } }
    STEP(x0, y0, z0, d0, g0 + 0)
    STEP(x1, y1, z1, d1, g0 + 1)
    STEP(x2, y2, z2, d2, g0 + 2)
    STEP(x3, y3, z3, d3, g0 + 3)
    STEP(x4, y4, z4, d4, g1 + 0)
    STEP(x5, y5, z5, d5, g1 + 1)
    STEP(x6, y6, z6, d6, g1 + 2)
    STEP(x7, y7, z7, d7, g1 + 3)

    // Pack [distBits:32 @17][invIdx:17 @0]; non-negative f32 bits are
    // order-preserving; invIdx breaks ties toward the SMALLEST index.
    u64 key = ((u64)__float_as_uint(best) << 17) | (u64)((NPTS - 1) - bidx);

    // Per-wave butterfly (parallel across all 16 waves).
#pragma unroll
    for (int m = 32; m >= 1; m >>= 1) {
      u64 o = __shfl_xor(key, m, 64);
      key = umax64(key, o);
    }
    if (lane == 0) wkeys[wave] = key;
    __syncthreads();

    if (wave == 0) {
      // Block reduce: lanes mirror wkeys[lane&15], 4-step butterfly.
      u64 k = wkeys[lane & 15];
#pragma unroll
      for (int m = 8; m >= 1; m >>= 1) {
        u64 o = __shfl_xor(k, m, 64);
        k = umax64(k, o);
      }
      u64* par = bslots + (size_t)(t & 1) * SUBBLOCKS;

      // Publish via atomic RMW (executes at MALL, keeps line L3-resident;
      // R6's plain store wrote a 32 B sector through to HBM every time).
      if (lane == 0) {
        (void)__hip_atomic_exchange(par + sub, ((u64)t << 49) | k,
                                    __ATOMIC_RELAXED, __HIP_MEMORY_SCOPE_AGENT);
      }

      // Poll via returning RMW: lanes 0..15 on 16 DISTINCT slots
      // (same-address RMWs would serialize at the MALL atomic unit).
      u64 v = 0;
      const bool poller = (lane < SUBBLOCKS);
      u64* pp = par + lane;
      for (;;) {
        if (poller) {
          v = __hip_atomic_fetch_add(pp, 0ull,
                                     __ATOMIC_RELAXED, __HIP_MEMORY_SCOPE_AGENT);
        }
        bool ok = !poller | ((unsigned)(v >> 49) == (unsigned)t);
        if (__ballot(ok) == ~0ull) break;
      }
#pragma unroll
      for (int m = 8; m >= 1; m >>= 1) {
        u64 o = __shfl_xor(v, m, 64);
        v = umax64(v, o);
      }
      if (lane == 0) winner_s = v;
    }
    __syncthreads();

    sel = (NPTS - 1) - (int)(winner_s & 0x1FFFF);

    if (sub == 0 && tid == 0) {
      outb[t]         = px[sel];
      outb[M + t]     = py[sel];
      outb[2 * M + t] = pz[sel];
    }
  }
}

extern "C" void kernel_launch(void* const* d_in, const int* in_sizes, int n_in,
                              void* d_out, int out_size, void* d_ws, size_t ws_size,
                              hipStream_t stream) {
  (void)in_sizes; (void)n_in; (void)ws_size;
  const float* points = (const float*)d_in[0];
  float* out = (float*)d_out;
  u64* slots = (u64*)d_ws;
  const int M = out_size / (NBATCH * 3);   // 2048

  // Zero barrier slots (stale tags must not alias t in 1..M-1).
  hipMemsetAsync(d_ws, 0, (size_t)NBATCH * 2 * SUBBLOCKS * sizeof(u64), stream);

  hipLaunchKernelGGL(fps_kernel, dim3(NBATCH * SUBBLOCKS), dim3(NTHREADS), 0,
                     stream, points, out, slots, M);
}